// Round 3
// baseline (380.011 us; speedup 1.0000x reference)
//
#include <hip/hip_runtime.h>
#include <cstdint>
#include <cstddef>

#define NIMG 32
#define NCLS 81
#define NC1  80
#define NBOX 8732
#define CAP  65536
#define TOPK 400
#define MAXOUT 100
#define KW   7          // 400 bits -> 7 u64 words
#define COLCAP 4096
#define WBUF 1280       // max candidates per wave: 64 boxes * 19 classes(p>0.05)
#define BDEC 128
#define BSEL 512

constexpr size_t TOTAL_S = (size_t)NIMG * NCLS * NBOX;

__device__ __forceinline__ unsigned int f2sort(float f) {
    unsigned int u = __float_as_uint(f);
    return (u & 0x80000000u) ? ~u : (u | 0x80000000u);
}

// ---------------- kernel 1: decode + LDS-staged softmax + candidate filter ----------------
__global__ __launch_bounds__(BDEC) void k_decode(const float* __restrict__ bboxes,
        const float* __restrict__ scores, const float* __restrict__ dbox,
        float4* __restrict__ oboxes, uint2* __restrict__ cand, int* __restrict__ cnt) {
    __shared__ float tile[NCLS * BDEC];     // 41.5 KB
    __shared__ uint2 lbuf[2 * WBUF];        // 20.5 KB
    int n = blockIdx.y;
    int b0 = blockIdx.x * BDEC;
    int tid = threadIdx.x;
    int lane = tid & 63;
    int wv = tid >> 6;

    // cooperative tile load: 81 rows x 128 floats, float4-vectorized
    const size_t sbase = (size_t)n * NCLS * NBOX + b0;
    const int NQ = NCLS * (BDEC / 4);   // 2592
    for (int idx = tid; idx < NQ; idx += BDEC) {
        int c = idx >> 5;           // row (class)
        int q = idx & 31;           // float4 within row
        size_t g = sbase + (size_t)c * NBOX + 4 * q;
        float4 v;
        if (g + 3 < TOTAL_S) {
            v = *reinterpret_cast<const float4*>(scores + g);
        } else {
            v.x = (g     < TOTAL_S) ? scores[g]     : 0.f;
            v.y = (g + 1 < TOTAL_S) ? scores[g + 1] : 0.f;
            v.z = (g + 2 < TOTAL_S) ? scores[g + 2] : 0.f;
            v.w = 0.f;
        }
        *reinterpret_cast<float4*>(&tile[c * BDEC + 4 * q]) = v;
    }

    int b = b0 + tid;
    bool live = (b < NBOX);
    bool go = false;
    if (live) {
        const float* bp = bboxes + (size_t)n * 4 * NBOX + b;
        float bx = bp[0], by = bp[NBOX], bw = bp[2 * NBOX], bh = bp[3 * NBOX];
        float4 d = reinterpret_cast<const float4*>(dbox)[b];
        float cx = 0.1f * bx * d.z + d.x;
        float cy = 0.1f * by * d.w + d.y;
        float ww = expf(0.2f * bw) * d.z;
        float hh = expf(0.2f * bh) * d.w;
        float l = cx - 0.5f * ww, t = cy - 0.5f * hh;
        float r = cx + 0.5f * ww, bo = cy + 0.5f * hh;
        l = fminf(fmaxf(l, 0.f), 1.f);  t  = fminf(fmaxf(t, 0.f), 1.f);
        r = fminf(fmaxf(r, 0.f), 1.f);  bo = fminf(fmaxf(bo, 0.f), 1.f);
        const float MINS = 1.0f / 300.0f;
        go = (r - l >= MINS) && (bo - t >= MINS);
        oboxes[(size_t)n * NBOX + b] = make_float4(l, t, r, bo);
    }
    __syncthreads();

    float m = -3.4e38f, s = 0.f;
    if (go) {
        for (int c = 0; c < NCLS; ++c) m = fmaxf(m, tile[c * BDEC + tid]);
        for (int c = 0; c < NCLS; ++c) s += expf(tile[c * BDEC + tid] - m);
    }

    int wn = 0;
    uint2* wl = lbuf + wv * WBUF;
    unsigned long long lmlt = (1ull << lane) - 1ull;
    for (int c = 1; c < NCLS; ++c) {
        bool v = false; float p = 0.f;
        if (go) {
            p = expf(tile[c * BDEC + tid] - m) / s;
            v = p > 0.05f;
        }
        unsigned long long mask = __ballot(v);
        if (v) {
            int pos = wn + (int)__popcll(mask & lmlt);
            if (pos < WBUF) wl[pos] = make_uint2(__float_as_uint(p),
                                                 (unsigned)(b * NC1 + (c - 1)));
        }
        wn += (int)__popcll(mask);
    }
    if (wn > WBUF) wn = WBUF;
    int base = 0;
    if (lane == 0) base = atomicAdd(&cnt[n], wn);
    base = __shfl(base, 0);
    uint2* cp = cand + (size_t)n * CAP;
    for (int i = lane; i < wn; i += 64) {
        int pos = base + i;
        if (pos < CAP) cp[pos] = wl[i];
    }
}

// ---------------- bitonic sort (descending), u64 keys in LDS, n = pow2 ----------------
__device__ void bitonic_desc(unsigned long long* arr, int n, int tid, int nt) {
    for (int k = 2; k <= n; k <<= 1) {
        for (int j = k >> 1; j > 0; j >>= 1) {
            __syncthreads();
            for (int i = tid; i < n; i += nt) {
                int ixj = i ^ j;
                if (ixj > i) {
                    unsigned long long a = arr[i], b = arr[ixj];
                    bool desc = ((i & k) == 0);
                    bool sw = desc ? (a < b) : (a > b);
                    if (sw) { arr[i] = b; arr[ixj] = a; }
                }
            }
        }
    }
    __syncthreads();
}

// next kept index >= from, fully unrolled so kp stays in registers
__device__ __forceinline__ int nms_next(const unsigned long long kp[KW], int from) {
    #pragma unroll
    for (int w = 0; w < KW; ++w) {
        int lo = w << 6;
        if (from < lo + 64) {
            int bshift = (from > lo) ? (from - lo) : 0;
            unsigned long long msk = (bshift == 0) ? ~0ull : (~0ull << bshift);
            unsigned long long mm = kp[w] & msk;
            if (mm) return lo + __ffsll((long long)mm) - 1;
        }
    }
    return TOPK;
}

// ---------------- kernel 2: per-image top-400 + NMS + top-100 + output ----------------
__global__ __launch_bounds__(BSEL) void k_select(const float4* __restrict__ boxes,
        const uint2* __restrict__ cand, const int* __restrict__ cnt,
        float* __restrict__ out) {
    __shared__ int hist[1024];
    __shared__ unsigned long long keys[COLCAP];   // later reused as suppression rows
    __shared__ float  s_score[TOPK];
    __shared__ float4 s_cbox[TOPK];
    __shared__ int    s_label[TOPK];
    __shared__ float4 s_ob[TOPK];
    __shared__ float  s_area[TOPK];
    __shared__ unsigned long long s_keep[KW];
    __shared__ unsigned long long finkeys[512];
    __shared__ int s_T, s_pos;

    int n = blockIdx.x;
    int tid = threadIdx.x;
    int lane = tid & 63;
    unsigned long long lmlt = (1ull << lane) - 1ull;
    int M = cnt[n]; if (M > CAP) M = CAP;
    const uint2* cp = cand + (size_t)n * CAP;

    for (int i = tid; i < 1024; i += BSEL) hist[i] = 0;
    if (tid == 0) s_pos = 0;
    __syncthreads();

    // histogram on top 16 bits of score (positive floats sort as unsigned)
    for (int i = tid; i < M; i += BSEL) {
        unsigned int bits = cp[i].x;
        int bk = (int)(bits >> 16) - 0x3D00;
        bk = max(0, min(1023, bk));
        atomicAdd(&hist[bk], 1);
    }
    __syncthreads();

    // threshold T = max t with suffix-count >= TOPK (0 if total < TOPK); wave-0 parallel
    if (tid < 64) {
        int sl = 0;
        #pragma unroll
        for (int t = 0; t < 16; ++t) sl += hist[tid * 16 + t];
        int incl = sl;
        #pragma unroll
        for (int off = 1; off < 64; off <<= 1) {
            int v = __shfl_down(incl, off);
            if (tid + off < 64) incl += v;
        }
        int xl = incl - sl;     // suffix of strictly-higher lanes
        int tc = -1, cum = xl;
        for (int t = 15; t >= 0; --t) {
            cum += hist[tid * 16 + t];
            if (cum >= TOPK) { tc = tid * 16 + t; break; }
        }
        #pragma unroll
        for (int off = 32; off > 0; off >>= 1)
            tc = max(tc, __shfl_xor(tc, off));
        if (tid == 0) s_T = max(tc, 0);
    }
    __syncthreads();
    int T = s_T;

    // collect candidates >= threshold bucket, wave-aggregated atomics
    int iters = (M + BSEL - 1) / BSEL;
    for (int it = 0; it < iters; ++it) {
        int i = it * BSEL + tid;
        bool pred = false; unsigned long long key = 0ull;
        if (i < M) {
            uint2 e = cp[i];
            int bk = (int)(e.x >> 16) - 0x3D00;
            bk = max(0, min(1023, bk));
            if (bk >= T) {
                pred = true;
                key = ((unsigned long long)e.x << 32) | (unsigned int)(~e.y);
            }
        }
        unsigned long long mask = __ballot(pred);
        int base = 0;
        if (lane == 0) {
            int cw = (int)__popcll(mask);
            if (cw) base = atomicAdd(&s_pos, cw);
        }
        base = __shfl(base, 0);
        if (pred) {
            int pos = base + (int)__popcll(mask & lmlt);
            if (pos < COLCAP) keys[pos] = key;
        }
    }
    __syncthreads();
    int ncol = min(s_pos, COLCAP);

    // sort only the smallest pow2 >= ncol (usually 512)
    int nsort = 512;
    while (nsort < ncol) nsort <<= 1;
    for (int i = ncol + tid; i < nsort; i += BSEL) keys[i] = 0ull;
    __syncthreads();
    bitonic_desc(keys, nsort, tid, BSEL);

    int nsel = min(TOPK, ncol);
    if (tid < TOPK) {
        int i = tid;
        if (i < nsel) {
            unsigned long long key = keys[i];
            unsigned int bits = (unsigned int)(key >> 32);
            unsigned int flat = ~(unsigned int)key;
            int bb = (int)(flat / NC1);
            int lab = (int)(flat - (unsigned)bb * NC1) + 1;
            float sc = __uint_as_float(bits);
            float4 cb = boxes[(size_t)n * NBOX + bb];
            s_score[i] = sc; s_cbox[i] = cb; s_label[i] = lab;
            float off = 2.0f * (float)lab;
            float4 ob = make_float4(cb.x + off, cb.y + off, cb.z + off, cb.w + off);
            s_ob[i] = ob;
            s_area[i] = fmaxf(ob.z - ob.x, 0.f) * fmaxf(ob.w - ob.y, 0.f);
        } else {
            s_score[i] = -1.0f;
            s_cbox[i] = make_float4(0.f, 0.f, 0.f, 0.f);
            s_label[i] = 0;
            s_ob[i] = make_float4(0.f, 0.f, 0.f, 0.f);
            s_area[i] = 0.f;
        }
    }
    __syncthreads();

    // suppression rows: thread i, uniform j (LDS broadcast), pipelined via unroll
    unsigned long long* rows = keys;
    if (tid < TOPK) {
        int i = tid;
        float4 oi = s_ob[i]; float ai = s_area[i];
        bool act = (i < nsel);
        #pragma unroll
        for (int w = 0; w < KW; ++w) {
            unsigned long long cur = 0ull;
            int j0 = w * 64;
            #pragma unroll 4
            for (int j = 0; j < 64; ++j) {
                float4 oj = s_ob[j0 + j];
                float aj = s_area[j0 + j];
                float lx = fmaxf(oi.x, oj.x), ly = fmaxf(oi.y, oj.y);
                float rx = fminf(oi.z, oj.z), ry = fminf(oi.w, oj.w);
                float inter = fmaxf(rx - lx, 0.f) * fmaxf(ry - ly, 0.f);
                float uni = fmaxf(ai + aj - inter, 1e-12f);
                cur |= ((unsigned long long)(inter / uni > 0.5f)) << j;
            }
            if (!act || (j0 + 63 <= i)) cur = 0ull;
            else if (j0 <= i) cur &= ~((1ull << (i - j0 + 1)) - 1ull);
            rows[(size_t)i * 8 + w] = cur;
        }
    }
    __syncthreads();

    // serial order-dependent suppression on one thread, keep mask in registers,
    // iterate only currently-kept i (exactly equivalent), speculative row prefetch
    if (tid == 0) {
        unsigned long long kp[KW];
        #pragma unroll
        for (int w = 0; w < KW; ++w) {
            int lo = w << 6;
            kp[w] = (nsel >= lo + 64) ? ~0ull
                  : (nsel <= lo ? 0ull : ((1ull << (nsel - lo)) - 1ull));
        }
        int i = nms_next(kp, 0);
        unsigned long long pr[KW];
        if (i < TOPK) {
            #pragma unroll
            for (int w = 0; w < KW; ++w) pr[w] = rows[(size_t)i * 8 + w];
        }
        while (i < TOPK) {
            int spec = nms_next(kp, i + 1);
            unsigned long long sr[KW];
            if (spec < TOPK) {
                #pragma unroll
                for (int w = 0; w < KW; ++w) sr[w] = rows[(size_t)spec * 8 + w];
            }
            #pragma unroll
            for (int w = 0; w < KW; ++w) kp[w] &= ~pr[w];
            int nx = nms_next(kp, i + 1);
            if (nx < TOPK) {
                if (nx == spec) {
                    #pragma unroll
                    for (int w = 0; w < KW; ++w) pr[w] = sr[w];
                } else {
                    #pragma unroll
                    for (int w = 0; w < KW; ++w) pr[w] = rows[(size_t)nx * 8 + w];
                }
            }
            i = nx;
        }
        #pragma unroll
        for (int w = 0; w < KW; ++w) s_keep[w] = kp[w];
    }
    __syncthreads();

    // final stable top-100 over 400 slots
    for (int i = tid; i < 512; i += BSEL) {
        unsigned long long key = 0ull;
        if (i < TOPK) {
            bool kb = (s_keep[i >> 6] >> (i & 63)) & 1ull;
            float fv = kb ? s_score[i] : -1.0f;
            key = ((unsigned long long)f2sort(fv) << 32) | (unsigned int)(~i);
        }
        finkeys[i] = key;
    }
    __syncthreads();
    bitonic_desc(finkeys, 512, tid, BSEL);

    float* obox = out;
    float* olab = out + (size_t)NIMG * MAXOUT * 4;
    float* osco = out + (size_t)NIMG * MAXOUT * 5;
    for (int k = tid; k < MAXOUT; k += BSEL) {
        unsigned long long key = finkeys[k];
        int slot = (int)(~(unsigned int)key);
        float4 cb = make_float4(0.f, 0.f, 0.f, 0.f);
        float lab = 0.f, sv = 0.f;
        if (slot >= 0 && slot < TOPK) {
            bool kb = (s_keep[slot >> 6] >> (slot & 63)) & 1ull;
            float fv = kb ? s_score[slot] : -1.0f;
            if (fv > 0.0f) {
                cb = s_cbox[slot];
                lab = (float)s_label[slot];
                sv = fv;
            }
        }
        size_t bo_ = ((size_t)n * MAXOUT + k) * 4;
        obox[bo_ + 0] = cb.x; obox[bo_ + 1] = cb.y; obox[bo_ + 2] = cb.z; obox[bo_ + 3] = cb.w;
        olab[(size_t)n * MAXOUT + k] = lab;
        osco[(size_t)n * MAXOUT + k] = sv;
    }
}

extern "C" void kernel_launch(void* const* d_in, const int* in_sizes, int n_in,
                              void* d_out, int out_size, void* d_ws, size_t ws_size,
                              hipStream_t stream) {
    (void)in_sizes; (void)n_in; (void)out_size; (void)ws_size;
    const float* bboxes = (const float*)d_in[0];
    const float* scores = (const float*)d_in[1];
    const float* dbox   = (const float*)d_in[2];
    float* out = (float*)d_out;

    char* ws = (char*)d_ws;
    size_t off = 0;
    float4* oboxes = (float4*)(ws + off); off += (size_t)NIMG * NBOX * sizeof(float4);
    int* cnt = (int*)(ws + off); off += 256;
    uint2* cand = (uint2*)(ws + off); off += (size_t)NIMG * CAP * sizeof(uint2);

    hipMemsetAsync(cnt, 0, NIMG * sizeof(int), stream);

    int gx = (NBOX + BDEC - 1) / BDEC;   // 69
    k_decode<<<dim3(gx, NIMG), BDEC, 0, stream>>>(bboxes, scores, dbox, oboxes, cand, cnt);
    k_select<<<NIMG, BSEL, 0, stream>>>(oboxes, cand, cnt, out);
}

// Round 4
// 218.841 us; speedup vs baseline: 1.7365x; 1.7365x over previous
//
#include <hip/hip_runtime.h>
#include <cstdint>
#include <cstddef>

#define NIMG 32
#define NCLS 81
#define NC1  80
#define NBOX 8732
#define NB4  2183          // NBOX / 4 exactly
#define CAP  65536
#define TOPK 400
#define MAXOUT 100
#define KW   7             // 400 bits -> 7 u64 words
#define COLCAP 2048
#define BDEC 128
#define MARGIN 1e-4f

__device__ __forceinline__ unsigned int f2sort(float f) {
    unsigned int u = __float_as_uint(f);
    return (u & 0x80000000u) ? ~u : (u | 0x80000000u);
}

// ============ kernel 1: decode + softmax + log-domain filter, 4 boxes/thread ============
__global__ __launch_bounds__(BDEC) void k_decode(const float* __restrict__ bboxes,
        const float* __restrict__ scores, const float* __restrict__ dbox,
        float4* __restrict__ oboxes, uint2* __restrict__ cand, int* __restrict__ cnt) {
    int n = blockIdx.y;
    int t = blockIdx.x * BDEC + threadIdx.x;
    int lane = threadIdx.x & 63;
    bool live = (t < NB4);
    int b0 = live ? t * 4 : 0;

    const float* sp = scores + (size_t)n * NCLS * NBOX + b0;

    // ---- box decode for 4 consecutive boxes ----
    bool go[4] = {false, false, false, false};
    if (live) {
        const float* bp = bboxes + (size_t)n * 4 * NBOX + b0;
        float4 bx = *reinterpret_cast<const float4*>(bp);
        float4 by = *reinterpret_cast<const float4*>(bp + NBOX);
        float4 bw = *reinterpret_cast<const float4*>(bp + 2 * NBOX);
        float4 bh = *reinterpret_cast<const float4*>(bp + 3 * NBOX);
        const float4* dbp = reinterpret_cast<const float4*>(dbox) + b0;
        float bxa[4] = {bx.x, bx.y, bx.z, bx.w};
        float bya[4] = {by.x, by.y, by.z, by.w};
        float bwa[4] = {bw.x, bw.y, bw.z, bw.w};
        float bha[4] = {bh.x, bh.y, bh.z, bh.w};
        #pragma unroll
        for (int j = 0; j < 4; ++j) {
            float4 d = dbp[j];
            float cx = 0.1f * bxa[j] * d.z + d.x;
            float cy = 0.1f * bya[j] * d.w + d.y;
            float ww = expf(0.2f * bwa[j]) * d.z;
            float hh = expf(0.2f * bha[j]) * d.w;
            float l = cx - 0.5f * ww, tt = cy - 0.5f * hh;
            float r = cx + 0.5f * ww, bo = cy + 0.5f * hh;
            l = fminf(fmaxf(l, 0.f), 1.f);  tt = fminf(fmaxf(tt, 0.f), 1.f);
            r = fminf(fmaxf(r, 0.f), 1.f);  bo = fminf(fmaxf(bo, 0.f), 1.f);
            const float MINS = 1.0f / 300.0f;
            go[j] = (r - l >= MINS) && (bo - tt >= MINS);
            oboxes[(size_t)n * NBOX + b0 + j] = make_float4(l, tt, r, bo);
        }
    }

    // ---- pass A: max over classes ----
    float mm[4] = {-3.4e38f, -3.4e38f, -3.4e38f, -3.4e38f};
    if (live) {
        #pragma unroll 4
        for (int c = 0; c < NCLS; ++c) {
            float4 v = *reinterpret_cast<const float4*>(sp + (size_t)c * NBOX);
            mm[0] = fmaxf(mm[0], v.x); mm[1] = fmaxf(mm[1], v.y);
            mm[2] = fmaxf(mm[2], v.z); mm[3] = fmaxf(mm[3], v.w);
        }
    }

    // ---- pass B: exact serial-order sum of exp(x - m) ----
    float ss[4] = {0.f, 0.f, 0.f, 0.f};
    if (live) {
        #pragma unroll 4
        for (int c = 0; c < NCLS; ++c) {
            float4 v = *reinterpret_cast<const float4*>(sp + (size_t)c * NBOX);
            ss[0] += expf(v.x - mm[0]); ss[1] += expf(v.y - mm[1]);
            ss[2] += expf(v.z - mm[2]); ss[3] += expf(v.w - mm[3]);
        }
    }

    float thr[4];
    #pragma unroll
    for (int j = 0; j < 4; ++j)
        thr[j] = go[j] ? logf(0.05f * ss[j]) : 3.4e38f;

    // ---- pass C: log-domain filter with exact gray-zone resolution ----
    unsigned long long mlo[4] = {0, 0, 0, 0};   // classes 1..64
    unsigned int       mhi[4] = {0, 0, 0, 0};   // classes 65..80
    if (live) {
        for (int c = 1; c < NCLS; ++c) {
            float4 v = *reinterpret_cast<const float4*>(sp + (size_t)c * NBOX);
            float va[4] = {v.x, v.y, v.z, v.w};
            #pragma unroll
            for (int j = 0; j < 4; ++j) {
                float d = va[j] - mm[j];
                bool bit;
                if (d > thr[j] + MARGIN)        bit = true;
                else if (d > thr[j] - MARGIN)   bit = (expf(d) / ss[j] > 0.05f);
                else                            bit = false;
                if (bit) {
                    if (c <= 64) mlo[j] |= 1ull << (c - 1);
                    else         mhi[j] |= 1u << (c - 65);
                }
            }
        }
    }

    // ---- pass D: wave-aggregated reservation + emit ----
    int nc = 0;
    #pragma unroll
    for (int j = 0; j < 4; ++j)
        nc += (int)__popcll(mlo[j]) + __popc(mhi[j]);

    int incl = nc;
    #pragma unroll
    for (int off = 1; off < 64; off <<= 1) {
        int u = __shfl_up(incl, off);
        if (lane >= off) incl += u;
    }
    int excl = incl - nc;
    int tot = __shfl(incl, 63);
    int base = 0;
    if (lane == 0 && tot > 0) base = atomicAdd(&cnt[n], tot);
    base = __shfl(base, 0);

    if (nc > 0) {
        int pos = base + excl;
        uint2* cp = cand + (size_t)n * CAP;
        #pragma unroll
        for (int j = 0; j < 4; ++j) {
            int b = b0 + j;
            unsigned long long ml = mlo[j];
            while (ml) {
                int bit = (int)__ffsll((long long)ml) - 1; ml &= ml - 1;
                int c = bit + 1;
                float x = sp[(size_t)c * NBOX + j];
                float p = expf(x - mm[j]) / ss[j];
                if (pos < CAP) cp[pos] = make_uint2(__float_as_uint(p),
                                                    (unsigned)(b * NC1 + (c - 1)));
                ++pos;
            }
            unsigned int mh = mhi[j];
            while (mh) {
                int bit = __ffs(mh) - 1; mh &= mh - 1;
                int c = bit + 65;
                float x = sp[(size_t)c * NBOX + j];
                float p = expf(x - mm[j]) / ss[j];
                if (pos < CAP) cp[pos] = make_uint2(__float_as_uint(p),
                                                    (unsigned)(b * NC1 + (c - 1)));
                ++pos;
            }
        }
    }
}

// ============ bitonic sort (descending), u64 keys in LDS, n = pow2 ============
__device__ void bitonic_desc(unsigned long long* arr, int n, int tid, int nt) {
    for (int k = 2; k <= n; k <<= 1) {
        for (int j = k >> 1; j > 0; j >>= 1) {
            __syncthreads();
            for (int i = tid; i < n; i += nt) {
                int ixj = i ^ j;
                if (ixj > i) {
                    unsigned long long a = arr[i], b = arr[ixj];
                    bool desc = ((i & k) == 0);
                    bool sw = desc ? (a < b) : (a > b);
                    if (sw) { arr[i] = b; arr[ixj] = a; }
                }
            }
        }
    }
    __syncthreads();
}

// ============ kernel 2: per-image top-400 selection, write records ============
__global__ __launch_bounds__(1024) void k_topk(const float4* __restrict__ boxes,
        const uint2* __restrict__ cand, const int* __restrict__ cnt,
        float* __restrict__ g_sc, float4* __restrict__ g_cb, int* __restrict__ g_lab,
        float4* __restrict__ g_ob, float* __restrict__ g_ar, int* __restrict__ g_nsel) {
    __shared__ int hist[1024];
    __shared__ unsigned long long keys[COLCAP];
    __shared__ int s_T, s_pos;

    int n = blockIdx.x;
    int tid = threadIdx.x;
    int lane = tid & 63;
    unsigned long long lmlt = (1ull << lane) - 1ull;
    int M = cnt[n]; if (M > CAP) M = CAP;
    const uint2* cp = cand + (size_t)n * CAP;

    hist[tid] = 0;
    if (tid == 0) s_pos = 0;
    __syncthreads();

    for (int i = tid; i < M; i += 1024) {
        unsigned int bits = cp[i].x;
        int bk = (int)(bits >> 16) - 0x3D00;
        bk = max(0, min(1023, bk));
        atomicAdd(&hist[bk], 1);
    }
    __syncthreads();

    // threshold T = max t with suffix-count >= TOPK (wave-0 parallel)
    if (tid < 64) {
        int sl = 0;
        #pragma unroll
        for (int t = 0; t < 16; ++t) sl += hist[tid * 16 + t];
        int incl = sl;
        #pragma unroll
        for (int off = 1; off < 64; off <<= 1) {
            int v = __shfl_down(incl, off);
            if (tid + off < 64) incl += v;
        }
        int xl = incl - sl;
        int tc = -1, cum = xl;
        for (int t = 15; t >= 0; --t) {
            cum += hist[tid * 16 + t];
            if (cum >= TOPK) { tc = tid * 16 + t; break; }
        }
        #pragma unroll
        for (int off = 32; off > 0; off >>= 1)
            tc = max(tc, __shfl_xor(tc, off));
        if (tid == 0) s_T = max(tc, 0);
    }
    __syncthreads();
    int T = s_T;

    int iters = (M + 1023) / 1024;
    for (int it = 0; it < iters; ++it) {
        int i = it * 1024 + tid;
        bool pred = false; unsigned long long key = 0ull;
        if (i < M) {
            uint2 e = cp[i];
            int bk = (int)(e.x >> 16) - 0x3D00;
            bk = max(0, min(1023, bk));
            if (bk >= T) {
                pred = true;
                key = ((unsigned long long)e.x << 32) | (unsigned int)(~e.y);
            }
        }
        unsigned long long mask = __ballot(pred);
        int base = 0;
        if (lane == 0) {
            int cw = (int)__popcll(mask);
            if (cw) base = atomicAdd(&s_pos, cw);
        }
        base = __shfl(base, 0);
        if (pred) {
            int pos = base + (int)__popcll(mask & lmlt);
            if (pos < COLCAP) keys[pos] = key;
        }
    }
    __syncthreads();
    int ncol = min(s_pos, COLCAP);

    int nsort = 512;
    while (nsort < ncol) nsort <<= 1;
    for (int i = ncol + tid; i < nsort; i += 1024) keys[i] = 0ull;
    __syncthreads();
    bitonic_desc(keys, nsort, tid, 1024);

    int nsel = min(TOPK, ncol);
    if (tid < TOPK) {
        int i = tid;
        float sc = -1.0f; float4 cb = make_float4(0.f, 0.f, 0.f, 0.f);
        int lab = 0; float4 ob = cb; float ar = 0.f;
        if (i < nsel) {
            unsigned long long key = keys[i];
            unsigned int bits = (unsigned int)(key >> 32);
            unsigned int flat = ~(unsigned int)key;
            int bb = (int)(flat / NC1);
            lab = (int)(flat - (unsigned)bb * NC1) + 1;
            sc = __uint_as_float(bits);
            cb = boxes[(size_t)n * NBOX + bb];
            float off = 2.0f * (float)lab;
            ob = make_float4(cb.x + off, cb.y + off, cb.z + off, cb.w + off);
            ar = fmaxf(ob.z - ob.x, 0.f) * fmaxf(ob.w - ob.y, 0.f);
        }
        size_t gi = (size_t)n * TOPK + i;
        g_sc[gi] = sc; g_cb[gi] = cb; g_lab[gi] = lab; g_ob[gi] = ob; g_ar[gi] = ar;
    }
    if (tid == 0) g_nsel[n] = nsel;
}

// ============ kernel 3: IoU suppression-mask words, fully parallel ============
__global__ __launch_bounds__(256) void k_iou(const float4* __restrict__ g_ob,
        const float* __restrict__ g_ar, const int* __restrict__ g_nsel,
        unsigned long long* __restrict__ g_rows) {
    __shared__ float4 s_ob[TOPK];
    __shared__ float  s_ar[TOPK];
    int n = blockIdx.y, w = blockIdx.x;
    int tid = threadIdx.x;
    for (int i = tid; i < TOPK; i += 256) {
        s_ob[i] = g_ob[(size_t)n * TOPK + i];
        s_ar[i] = g_ar[(size_t)n * TOPK + i];
    }
    __syncthreads();
    int nsel = g_nsel[n];
    int j0 = w * 64;
    for (int i = tid; i < TOPK; i += 256) {
        unsigned long long cur = 0ull;
        if (i < nsel) {
            float4 oi = s_ob[i]; float ai = s_ar[i];
            int jend = min(j0 + 64, nsel);
            for (int j = j0; j < jend; ++j) {
                if (j > i) {
                    float4 oj = s_ob[j];
                    float lx = fmaxf(oi.x, oj.x), ly = fmaxf(oi.y, oj.y);
                    float rx = fminf(oi.z, oj.z), ry = fminf(oi.w, oj.w);
                    float inter = fmaxf(rx - lx, 0.f) * fmaxf(ry - ly, 0.f);
                    float uni = fmaxf(ai + s_ar[j] - inter, 1e-12f);
                    cur |= ((unsigned long long)(inter / uni > 0.5f)) << (j - j0);
                }
            }
        }
        g_rows[((size_t)n * TOPK + i) * 8 + w] = cur;
    }
}

// ============ kernel 4: serial NMS + final top-100 + output ============
__global__ __launch_bounds__(512) void k_nms(const unsigned long long* __restrict__ g_rows,
        const float* __restrict__ g_sc, const float4* __restrict__ g_cb,
        const int* __restrict__ g_lab, const int* __restrict__ g_nsel,
        float* __restrict__ out) {
    __shared__ unsigned long long s_rows[TOPK * KW];
    __shared__ float  s_score[TOPK];
    __shared__ int    s_label[TOPK];
    __shared__ float4 s_cbox[TOPK];
    __shared__ unsigned long long s_keep[KW];
    __shared__ unsigned long long finkeys[512];

    int n = blockIdx.x;
    int tid = threadIdx.x;
    int nsel = g_nsel[n];

    for (int i = tid; i < TOPK * KW; i += 512) {
        int r = i / KW, w = i - r * KW;
        s_rows[r * KW + w] = g_rows[((size_t)n * TOPK + r) * 8 + w];
    }
    for (int i = tid; i < TOPK; i += 512) {
        size_t gi = (size_t)n * TOPK + i;
        s_score[i] = g_sc[gi];
        s_label[i] = g_lab[gi];
        s_cbox[i]  = g_cb[gi];
    }
    __syncthreads();

    // lane-parallel serial suppression: lane w owns keep word w, prefetch next row
    if (tid < 64) {
        int lane = tid;
        unsigned long long keepw = 0ull;
        if (lane < KW) {
            int lo = lane << 6;
            keepw = (nsel >= lo + 64) ? ~0ull
                  : (nsel <= lo ? 0ull : ((1ull << (nsel - lo)) - 1ull));
        }
        unsigned long long row = (lane < KW && nsel > 0) ? s_rows[lane] : 0ull;
        for (int i = 0; i < nsel; ++i) {
            unsigned long long nrow = (lane < KW && (i + 1) < nsel)
                                      ? s_rows[(i + 1) * KW + lane] : 0ull;
            unsigned long long kwv = __shfl(keepw, i >> 6);
            if ((kwv >> (i & 63)) & 1ull) keepw &= ~row;
            row = nrow;
        }
        if (lane < KW) s_keep[lane] = keepw;
    }
    __syncthreads();

    for (int i = tid; i < 512; i += 512) {
        unsigned long long key = 0ull;
        if (i < TOPK) {
            bool kb = (s_keep[i >> 6] >> (i & 63)) & 1ull;
            float fv = kb ? s_score[i] : -1.0f;
            key = ((unsigned long long)f2sort(fv) << 32) | (unsigned int)(~i);
        }
        finkeys[i] = key;
    }
    __syncthreads();
    bitonic_desc(finkeys, 512, tid, 512);

    float* obox = out;
    float* olab = out + (size_t)NIMG * MAXOUT * 4;
    float* osco = out + (size_t)NIMG * MAXOUT * 5;
    for (int k = tid; k < MAXOUT; k += 512) {
        unsigned long long key = finkeys[k];
        int slot = (int)(~(unsigned int)key);
        float4 cb = make_float4(0.f, 0.f, 0.f, 0.f);
        float lab = 0.f, sv = 0.f;
        if (slot >= 0 && slot < TOPK) {
            bool kb = (s_keep[slot >> 6] >> (slot & 63)) & 1ull;
            float fv = kb ? s_score[slot] : -1.0f;
            if (fv > 0.0f) {
                cb = s_cbox[slot];
                lab = (float)s_label[slot];
                sv = fv;
            }
        }
        size_t bo_ = ((size_t)n * MAXOUT + k) * 4;
        obox[bo_ + 0] = cb.x; obox[bo_ + 1] = cb.y; obox[bo_ + 2] = cb.z; obox[bo_ + 3] = cb.w;
        olab[(size_t)n * MAXOUT + k] = lab;
        osco[(size_t)n * MAXOUT + k] = sv;
    }
}

extern "C" void kernel_launch(void* const* d_in, const int* in_sizes, int n_in,
                              void* d_out, int out_size, void* d_ws, size_t ws_size,
                              hipStream_t stream) {
    (void)in_sizes; (void)n_in; (void)out_size; (void)ws_size;
    const float* bboxes = (const float*)d_in[0];
    const float* scores = (const float*)d_in[1];
    const float* dbox   = (const float*)d_in[2];
    float* out = (float*)d_out;

    char* ws = (char*)d_ws;
    size_t off = 0;
    float4* oboxes = (float4*)(ws + off); off += (size_t)NIMG * NBOX * sizeof(float4);
    int* cnt = (int*)(ws + off); off += 256;
    uint2* cand = (uint2*)(ws + off); off += (size_t)NIMG * CAP * sizeof(uint2);
    float* g_sc = (float*)(ws + off); off += (size_t)NIMG * TOPK * sizeof(float);
    float4* g_cb = (float4*)(ws + off); off += (size_t)NIMG * TOPK * sizeof(float4);
    int* g_lab = (int*)(ws + off); off += (size_t)NIMG * TOPK * sizeof(int);
    float4* g_ob = (float4*)(ws + off); off += (size_t)NIMG * TOPK * sizeof(float4);
    float* g_ar = (float*)(ws + off); off += (size_t)NIMG * TOPK * sizeof(float);
    int* g_nsel = (int*)(ws + off); off += 256;
    unsigned long long* g_rows = (unsigned long long*)(ws + off);
    off += (size_t)NIMG * TOPK * 8 * sizeof(unsigned long long);

    hipMemsetAsync(cnt, 0, NIMG * sizeof(int), stream);

    int gx = (NB4 + BDEC - 1) / BDEC;   // 18
    k_decode<<<dim3(gx, NIMG), BDEC, 0, stream>>>(bboxes, scores, dbox, oboxes, cand, cnt);
    k_topk<<<NIMG, 1024, 0, stream>>>(oboxes, cand, cnt, g_sc, g_cb, g_lab, g_ob, g_ar, g_nsel);
    k_iou<<<dim3(KW, NIMG), 256, 0, stream>>>(g_ob, g_ar, g_nsel, g_rows);
    k_nms<<<NIMG, 512, 0, stream>>>(g_rows, g_sc, g_cb, g_lab, g_nsel, out);
}

// Round 5
// 192.948 us; speedup vs baseline: 1.9695x; 1.1342x over previous
//
#include <hip/hip_runtime.h>
#include <cstdint>
#include <cstddef>

#define NIMG 32
#define NCLS 81
#define NC1  80
#define NBOX 8732
#define CAP  65536
#define TOPK 400
#define MAXOUT 100
#define KW   7             // 400 bits -> 7 u64 words
#define COLCAP 2048
#define BDEC 256
#define MARGIN 1e-4f

__device__ __forceinline__ unsigned int f2sort(float f) {
    unsigned int u = __float_as_uint(f);
    return (u & 0x80000000u) ? ~u : (u | 0x80000000u);
}

// ============ kernel 1: decode + register-resident softmax + filter, 1 box/thread ============
__global__ __launch_bounds__(BDEC) void k_decode(const float* __restrict__ bboxes,
        const float* __restrict__ scores, const float* __restrict__ dbox,
        float4* __restrict__ oboxes, uint2* __restrict__ cand, int* __restrict__ cnt) {
    int n = blockIdx.y;
    int b = blockIdx.x * BDEC + threadIdx.x;
    int lane = threadIdx.x & 63;
    bool live = (b < NBOX);
    int bs = live ? b : 0;

    // ---- box decode ----
    bool go = false;
    if (live) {
        const float* bp = bboxes + (size_t)n * 4 * NBOX + b;
        float bx = bp[0], by = bp[NBOX], bw = bp[2 * NBOX], bh = bp[3 * NBOX];
        float4 d = reinterpret_cast<const float4*>(dbox)[b];
        float cx = 0.1f * bx * d.z + d.x;
        float cy = 0.1f * by * d.w + d.y;
        float ww = expf(0.2f * bw) * d.z;
        float hh = expf(0.2f * bh) * d.w;
        float l = cx - 0.5f * ww, tt = cy - 0.5f * hh;
        float r = cx + 0.5f * ww, bo = cy + 0.5f * hh;
        l = fminf(fmaxf(l, 0.f), 1.f);  tt = fminf(fmaxf(tt, 0.f), 1.f);
        r = fminf(fmaxf(r, 0.f), 1.f);  bo = fminf(fmaxf(bo, 0.f), 1.f);
        const float MINS = 1.0f / 300.0f;
        go = (r - l >= MINS) && (bo - tt >= MINS);
        oboxes[(size_t)n * NBOX + b] = make_float4(l, tt, r, bo);
    }

    // ---- single pass: all 81 class scores into registers (static indexing only) ----
    const float* sp = scores + (size_t)n * NCLS * NBOX + bs;
    float sc[NCLS];
    #pragma unroll
    for (int c = 0; c < NCLS; ++c) sc[c] = sp[(size_t)c * NBOX];

    // max over classes (sequential fmax chain, same order as reference)
    float m = -3.4e38f;
    #pragma unroll
    for (int c = 0; c < NCLS; ++c) m = fmaxf(m, sc[c]);

    // exact serial-order sum of exp(x - m)
    float ss = 0.f;
    #pragma unroll
    for (int c = 0; c < NCLS; ++c) ss += expf(sc[c] - m);

    float thr = go ? logf(0.05f * ss) : 3.4e38f;

    // ---- log-domain filter with exact gray-zone resolution ----
    unsigned long long mlo = 0ull;   // classes 1..64
    unsigned int       mhi = 0u;     // classes 65..80
    #pragma unroll
    for (int c = 1; c < NCLS; ++c) {
        float d = sc[c] - m;
        bool bit;
        if (d > thr + MARGIN)        bit = true;
        else if (d > thr - MARGIN)   bit = (expf(d) / ss > 0.05f);
        else                         bit = false;
        if (bit) {
            if (c <= 64) mlo |= 1ull << (c - 1);
            else         mhi |= 1u << (c - 65);
        }
    }

    // ---- wave-aggregated reservation ----
    int nc = (int)__popcll(mlo) + __popc(mhi);
    int incl = nc;
    #pragma unroll
    for (int off = 1; off < 64; off <<= 1) {
        int u = __shfl_up(incl, off);
        if (lane >= off) incl += u;
    }
    int excl = incl - nc;
    int tot = __shfl(incl, 63);
    int base = 0;
    if (lane == 0 && tot > 0) base = atomicAdd(&cnt[n], tot);
    base = __shfl(base, 0);

    // ---- emit (fully unrolled; sc[c] static) ----
    if (nc > 0) {
        int pos = base + excl;
        uint2* cp = cand + (size_t)n * CAP;
        #pragma unroll
        for (int c = 1; c < NCLS; ++c) {
            bool bit = (c <= 64) ? ((mlo >> (c - 1)) & 1ull) : ((mhi >> (c - 65)) & 1u);
            if (bit) {
                float p = expf(sc[c] - m) / ss;
                if (pos < CAP) cp[pos] = make_uint2(__float_as_uint(p),
                                                    (unsigned)(b * NC1 + (c - 1)));
                ++pos;
            }
        }
    }
}

// ============ bitonic sort (descending), u64 keys in LDS, n = pow2 ============
__device__ void bitonic_desc(unsigned long long* arr, int n, int tid, int nt) {
    for (int k = 2; k <= n; k <<= 1) {
        for (int j = k >> 1; j > 0; j >>= 1) {
            __syncthreads();
            for (int i = tid; i < n; i += nt) {
                int ixj = i ^ j;
                if (ixj > i) {
                    unsigned long long a = arr[i], b = arr[ixj];
                    bool desc = ((i & k) == 0);
                    bool sw = desc ? (a < b) : (a > b);
                    if (sw) { arr[i] = b; arr[ixj] = a; }
                }
            }
        }
    }
    __syncthreads();
}

// ============ kernel 2: per-image top-400 selection, write records ============
__global__ __launch_bounds__(1024) void k_topk(const float4* __restrict__ boxes,
        const uint2* __restrict__ cand, const int* __restrict__ cnt,
        float* __restrict__ g_sc, float4* __restrict__ g_cb, int* __restrict__ g_lab,
        float4* __restrict__ g_ob, float* __restrict__ g_ar, int* __restrict__ g_nsel) {
    __shared__ int hist[1024];
    __shared__ unsigned long long keys[COLCAP];
    __shared__ int s_T, s_pos;

    int n = blockIdx.x;
    int tid = threadIdx.x;
    int lane = tid & 63;
    unsigned long long lmlt = (1ull << lane) - 1ull;
    int M = cnt[n]; if (M > CAP) M = CAP;
    const uint2* cp = cand + (size_t)n * CAP;

    hist[tid] = 0;
    if (tid == 0) s_pos = 0;
    __syncthreads();

    for (int i = tid; i < M; i += 1024) {
        unsigned int bits = cp[i].x;
        int bk = (int)(bits >> 16) - 0x3D00;
        bk = max(0, min(1023, bk));
        atomicAdd(&hist[bk], 1);
    }
    __syncthreads();

    // threshold T = max t with suffix-count >= TOPK (wave-0 parallel)
    if (tid < 64) {
        int sl = 0;
        #pragma unroll
        for (int t = 0; t < 16; ++t) sl += hist[tid * 16 + t];
        int incl = sl;
        #pragma unroll
        for (int off = 1; off < 64; off <<= 1) {
            int v = __shfl_down(incl, off);
            if (tid + off < 64) incl += v;
        }
        int xl = incl - sl;
        int tc = -1, cum = xl;
        for (int t = 15; t >= 0; --t) {
            cum += hist[tid * 16 + t];
            if (cum >= TOPK) { tc = tid * 16 + t; break; }
        }
        #pragma unroll
        for (int off = 32; off > 0; off >>= 1)
            tc = max(tc, __shfl_xor(tc, off));
        if (tid == 0) s_T = max(tc, 0);
    }
    __syncthreads();
    int T = s_T;

    int iters = (M + 1023) / 1024;
    for (int it = 0; it < iters; ++it) {
        int i = it * 1024 + tid;
        bool pred = false; unsigned long long key = 0ull;
        if (i < M) {
            uint2 e = cp[i];
            int bk = (int)(e.x >> 16) - 0x3D00;
            bk = max(0, min(1023, bk));
            if (bk >= T) {
                pred = true;
                key = ((unsigned long long)e.x << 32) | (unsigned int)(~e.y);
            }
        }
        unsigned long long mask = __ballot(pred);
        int base = 0;
        if (lane == 0) {
            int cw = (int)__popcll(mask);
            if (cw) base = atomicAdd(&s_pos, cw);
        }
        base = __shfl(base, 0);
        if (pred) {
            int pos = base + (int)__popcll(mask & lmlt);
            if (pos < COLCAP) keys[pos] = key;
        }
    }
    __syncthreads();
    int ncol = min(s_pos, COLCAP);

    int nsort = 512;
    while (nsort < ncol) nsort <<= 1;
    for (int i = ncol + tid; i < nsort; i += 1024) keys[i] = 0ull;
    __syncthreads();
    bitonic_desc(keys, nsort, tid, 1024);

    int nsel = min(TOPK, ncol);
    if (tid < TOPK) {
        int i = tid;
        float sc = -1.0f; float4 cb = make_float4(0.f, 0.f, 0.f, 0.f);
        int lab = 0; float4 ob = cb; float ar = 0.f;
        if (i < nsel) {
            unsigned long long key = keys[i];
            unsigned int bits = (unsigned int)(key >> 32);
            unsigned int flat = ~(unsigned int)key;
            int bb = (int)(flat / NC1);
            lab = (int)(flat - (unsigned)bb * NC1) + 1;
            sc = __uint_as_float(bits);
            cb = boxes[(size_t)n * NBOX + bb];
            float off = 2.0f * (float)lab;
            ob = make_float4(cb.x + off, cb.y + off, cb.z + off, cb.w + off);
            ar = fmaxf(ob.z - ob.x, 0.f) * fmaxf(ob.w - ob.y, 0.f);
        }
        size_t gi = (size_t)n * TOPK + i;
        g_sc[gi] = sc; g_cb[gi] = cb; g_lab[gi] = lab; g_ob[gi] = ob; g_ar[gi] = ar;
    }
    if (tid == 0) g_nsel[n] = nsel;
}

// ============ kernel 3: IoU suppression-mask words, fully parallel ============
__global__ __launch_bounds__(256) void k_iou(const float4* __restrict__ g_ob,
        const float* __restrict__ g_ar, const int* __restrict__ g_nsel,
        unsigned long long* __restrict__ g_rows) {
    __shared__ float4 s_ob[TOPK];
    __shared__ float  s_ar[TOPK];
    int n = blockIdx.y, w = blockIdx.x;
    int tid = threadIdx.x;
    for (int i = tid; i < TOPK; i += 256) {
        s_ob[i] = g_ob[(size_t)n * TOPK + i];
        s_ar[i] = g_ar[(size_t)n * TOPK + i];
    }
    __syncthreads();
    int nsel = g_nsel[n];
    int j0 = w * 64;
    for (int i = tid; i < TOPK; i += 256) {
        unsigned long long cur = 0ull;
        if (i < nsel) {
            float4 oi = s_ob[i]; float ai = s_ar[i];
            int jend = min(j0 + 64, nsel);
            for (int j = j0; j < jend; ++j) {
                if (j > i) {
                    float4 oj = s_ob[j];
                    float lx = fmaxf(oi.x, oj.x), ly = fmaxf(oi.y, oj.y);
                    float rx = fminf(oi.z, oj.z), ry = fminf(oi.w, oj.w);
                    float inter = fmaxf(rx - lx, 0.f) * fmaxf(ry - ly, 0.f);
                    float uni = fmaxf(ai + s_ar[j] - inter, 1e-12f);
                    cur |= ((unsigned long long)(inter / uni > 0.5f)) << (j - j0);
                }
            }
        }
        g_rows[((size_t)n * TOPK + i) * 8 + w] = cur;
    }
}

// ============ kernel 4: serial NMS + final top-100 + output ============
__global__ __launch_bounds__(512) void k_nms(const unsigned long long* __restrict__ g_rows,
        const float* __restrict__ g_sc, const float4* __restrict__ g_cb,
        const int* __restrict__ g_lab, const int* __restrict__ g_nsel,
        float* __restrict__ out) {
    __shared__ unsigned long long s_rows[TOPK * KW];
    __shared__ float  s_score[TOPK];
    __shared__ int    s_label[TOPK];
    __shared__ float4 s_cbox[TOPK];
    __shared__ unsigned long long s_keep[KW];
    __shared__ unsigned long long finkeys[512];

    int n = blockIdx.x;
    int tid = threadIdx.x;
    int nsel = g_nsel[n];

    for (int i = tid; i < TOPK * KW; i += 512) {
        int r = i / KW, w = i - r * KW;
        s_rows[r * KW + w] = g_rows[((size_t)n * TOPK + r) * 8 + w];
    }
    for (int i = tid; i < TOPK; i += 512) {
        size_t gi = (size_t)n * TOPK + i;
        s_score[i] = g_sc[gi];
        s_label[i] = g_lab[gi];
        s_cbox[i]  = g_cb[gi];
    }
    __syncthreads();

    // lane-parallel serial suppression: lane w owns keep word w, prefetch next row
    if (tid < 64) {
        int lane = tid;
        unsigned long long keepw = 0ull;
        if (lane < KW) {
            int lo = lane << 6;
            keepw = (nsel >= lo + 64) ? ~0ull
                  : (nsel <= lo ? 0ull : ((1ull << (nsel - lo)) - 1ull));
        }
        unsigned long long row = (lane < KW && nsel > 0) ? s_rows[lane] : 0ull;
        for (int i = 0; i < nsel; ++i) {
            unsigned long long nrow = (lane < KW && (i + 1) < nsel)
                                      ? s_rows[(i + 1) * KW + lane] : 0ull;
            unsigned long long kwv = __shfl(keepw, i >> 6);
            if ((kwv >> (i & 63)) & 1ull) keepw &= ~row;
            row = nrow;
        }
        if (lane < KW) s_keep[lane] = keepw;
    }
    __syncthreads();

    for (int i = tid; i < 512; i += 512) {
        unsigned long long key = 0ull;
        if (i < TOPK) {
            bool kb = (s_keep[i >> 6] >> (i & 63)) & 1ull;
            float fv = kb ? s_score[i] : -1.0f;
            key = ((unsigned long long)f2sort(fv) << 32) | (unsigned int)(~i);
        }
        finkeys[i] = key;
    }
    __syncthreads();
    bitonic_desc(finkeys, 512, tid, 512);

    float* obox = out;
    float* olab = out + (size_t)NIMG * MAXOUT * 4;
    float* osco = out + (size_t)NIMG * MAXOUT * 5;
    for (int k = tid; k < MAXOUT; k += 512) {
        unsigned long long key = finkeys[k];
        int slot = (int)(~(unsigned int)key);
        float4 cb = make_float4(0.f, 0.f, 0.f, 0.f);
        float lab = 0.f, sv = 0.f;
        if (slot >= 0 && slot < TOPK) {
            bool kb = (s_keep[slot >> 6] >> (slot & 63)) & 1ull;
            float fv = kb ? s_score[slot] : -1.0f;
            if (fv > 0.0f) {
                cb = s_cbox[slot];
                lab = (float)s_label[slot];
                sv = fv;
            }
        }
        size_t bo_ = ((size_t)n * MAXOUT + k) * 4;
        obox[bo_ + 0] = cb.x; obox[bo_ + 1] = cb.y; obox[bo_ + 2] = cb.z; obox[bo_ + 3] = cb.w;
        olab[(size_t)n * MAXOUT + k] = lab;
        osco[(size_t)n * MAXOUT + k] = sv;
    }
}

extern "C" void kernel_launch(void* const* d_in, const int* in_sizes, int n_in,
                              void* d_out, int out_size, void* d_ws, size_t ws_size,
                              hipStream_t stream) {
    (void)in_sizes; (void)n_in; (void)out_size; (void)ws_size;
    const float* bboxes = (const float*)d_in[0];
    const float* scores = (const float*)d_in[1];
    const float* dbox   = (const float*)d_in[2];
    float* out = (float*)d_out;

    char* ws = (char*)d_ws;
    size_t off = 0;
    float4* oboxes = (float4*)(ws + off); off += (size_t)NIMG * NBOX * sizeof(float4);
    int* cnt = (int*)(ws + off); off += 256;
    uint2* cand = (uint2*)(ws + off); off += (size_t)NIMG * CAP * sizeof(uint2);
    float* g_sc = (float*)(ws + off); off += (size_t)NIMG * TOPK * sizeof(float);
    float4* g_cb = (float4*)(ws + off); off += (size_t)NIMG * TOPK * sizeof(float4);
    int* g_lab = (int*)(ws + off); off += (size_t)NIMG * TOPK * sizeof(int);
    float4* g_ob = (float4*)(ws + off); off += (size_t)NIMG * TOPK * sizeof(float4);
    float* g_ar = (float*)(ws + off); off += (size_t)NIMG * TOPK * sizeof(float);
    int* g_nsel = (int*)(ws + off); off += 256;
    unsigned long long* g_rows = (unsigned long long*)(ws + off);
    off += (size_t)NIMG * TOPK * 8 * sizeof(unsigned long long);

    hipMemsetAsync(cnt, 0, NIMG * sizeof(int), stream);

    int gx = (NBOX + BDEC - 1) / BDEC;   // 35
    k_decode<<<dim3(gx, NIMG), BDEC, 0, stream>>>(bboxes, scores, dbox, oboxes, cand, cnt);
    k_topk<<<NIMG, 1024, 0, stream>>>(oboxes, cand, cnt, g_sc, g_cb, g_lab, g_ob, g_ar, g_nsel);
    k_iou<<<dim3(KW, NIMG), 256, 0, stream>>>(g_ob, g_ar, g_nsel, g_rows);
    k_nms<<<NIMG, 512, 0, stream>>>(g_rows, g_sc, g_cb, g_lab, g_nsel, out);
}

// Round 6
// 188.747 us; speedup vs baseline: 2.0133x; 1.0223x over previous
//
#include <hip/hip_runtime.h>
#include <cstdint>
#include <cstddef>

#define NIMG 32
#define NCLS 81
#define NC1  80
#define NBOX 8732
#define CAP  65536
#define TOPK 400
#define MAXOUT 100
#define KW   7             // 400 bits -> 7 u64 words
#define COLCAP 2048
#define BDEC 256

__device__ __forceinline__ unsigned int f2sort(float f) {
    unsigned int u = __float_as_uint(f);
    return (u & 0x80000000u) ? ~u : (u | 0x80000000u);
}

// ============ kernel 1: decode + register-resident softmax + filter, 1 box/thread ============
__global__ __launch_bounds__(BDEC) void k_decode(const float* __restrict__ bboxes,
        const float* __restrict__ scores, const float* __restrict__ dbox,
        float4* __restrict__ oboxes, uint2* __restrict__ cand, int* __restrict__ cnt) {
    int n = blockIdx.y;
    int b = blockIdx.x * BDEC + threadIdx.x;
    int lane = threadIdx.x & 63;
    bool live = (b < NBOX);
    int bs = live ? b : 0;

    // ---- issue all 81 class-score loads first (static indexing -> registers) ----
    const float* sp = scores + (size_t)n * NCLS * NBOX + bs;
    float sc[NCLS];
    #pragma unroll
    for (int c = 0; c < NCLS; ++c) sc[c] = sp[(size_t)c * NBOX];

    // ---- box decode (overlaps score-load latency) ----
    bool go = false;
    float l = 0.f, tt = 0.f, r = 0.f, bo = 0.f;
    if (live) {
        const float* bp = bboxes + (size_t)n * 4 * NBOX + b;
        float bx = bp[0], by = bp[NBOX], bw = bp[2 * NBOX], bh = bp[3 * NBOX];
        float4 d = reinterpret_cast<const float4*>(dbox)[b];
        float cx = 0.1f * bx * d.z + d.x;
        float cy = 0.1f * by * d.w + d.y;
        float ww = expf(0.2f * bw) * d.z;
        float hh = expf(0.2f * bh) * d.w;
        l = cx - 0.5f * ww;  tt = cy - 0.5f * hh;
        r = cx + 0.5f * ww;  bo = cy + 0.5f * hh;
        l = fminf(fmaxf(l, 0.f), 1.f);  tt = fminf(fmaxf(tt, 0.f), 1.f);
        r = fminf(fmaxf(r, 0.f), 1.f);  bo = fminf(fmaxf(bo, 0.f), 1.f);
        const float MINS = 1.0f / 300.0f;
        go = (r - l >= MINS) && (bo - tt >= MINS);
    }

    // ---- max over classes (sequential fmax chain, same order as reference) ----
    float m = -3.4e38f;
    #pragma unroll
    for (int c = 0; c < NCLS; ++c) m = fmaxf(m, sc[c]);

    // ---- exp in place + exact serial-order sum ----
    float ss = 0.f;
    #pragma unroll
    for (int c = 0; c < NCLS; ++c) { sc[c] = expf(sc[c] - m); ss += sc[c]; }

    // ---- probabilities in place + filter (reference arithmetic: divide then compare) ----
    unsigned long long mlo = 0ull;   // classes 1..64
    unsigned int       mhi = 0u;     // classes 65..80
    #pragma unroll
    for (int c = 1; c < NCLS; ++c) {
        float p = sc[c] / ss;
        sc[c] = p;
        if (go && (p > 0.05f)) {
            if (c <= 64) mlo |= 1ull << (c - 1);
            else         mhi |= 1u << (c - 65);
        }
    }

    // ---- wave-aggregated reservation ----
    int nc = (int)__popcll(mlo) + __popc(mhi);
    int incl = nc;
    #pragma unroll
    for (int off = 1; off < 64; off <<= 1) {
        int u = __shfl_up(incl, off);
        if (lane >= off) incl += u;
    }
    int excl = incl - nc;
    int tot = __shfl(incl, 63);
    int base = 0;
    if (lane == 0 && tot > 0) base = atomicAdd(&cnt[n], tot);
    base = __shfl(base, 0);

    // ---- emit (p already in registers; fully static indexing) ----
    if (nc > 0) {
        int pos = base + excl;
        uint2* cp = cand + (size_t)n * CAP;
        #pragma unroll
        for (int c = 1; c < NCLS; ++c) {
            bool bit = (c <= 64) ? (((mlo >> (c - 1)) & 1ull) != 0)
                                 : (((mhi >> (c - 65)) & 1u) != 0);
            if (bit) {
                if (pos < CAP) cp[pos] = make_uint2(__float_as_uint(sc[c]),
                                                    (unsigned)(b * NC1 + (c - 1)));
                ++pos;
            }
        }
    }

    // only boxes that emitted candidates are ever read back
    if (live && nc > 0) oboxes[(size_t)n * NBOX + b] = make_float4(l, tt, r, bo);
}

// ============ bitonic sort (descending), u64 keys in LDS, n = pow2 ============
__device__ void bitonic_desc(unsigned long long* arr, int n, int tid, int nt) {
    for (int k = 2; k <= n; k <<= 1) {
        for (int j = k >> 1; j > 0; j >>= 1) {
            __syncthreads();
            for (int i = tid; i < n; i += nt) {
                int ixj = i ^ j;
                if (ixj > i) {
                    unsigned long long a = arr[i], b = arr[ixj];
                    bool desc = ((i & k) == 0);
                    bool sw = desc ? (a < b) : (a > b);
                    if (sw) { arr[i] = b; arr[ixj] = a; }
                }
            }
        }
    }
    __syncthreads();
}

// ============ kernel 2: merged top-400 + IoU + NMS + top-100 + output ============
__global__ __launch_bounds__(1024) void k_select(const float4* __restrict__ boxes,
        const uint2* __restrict__ cand, const int* __restrict__ cnt,
        float* __restrict__ out) {
    __shared__ union { int hist[1024]; unsigned long long fin[512]; } hf;
    __shared__ unsigned long long keys[COLCAP];
    __shared__ float  s_score[TOPK];
    __shared__ float4 s_cbox[TOPK];
    __shared__ int    s_label[TOPK];
    __shared__ float4 s_ob[TOPK];
    __shared__ float  s_area[TOPK];
    __shared__ unsigned long long rows[TOPK * KW];
    __shared__ unsigned long long s_keep[KW];
    __shared__ int s_T, s_pos;

    int n = blockIdx.x;
    int tid = threadIdx.x;
    int lane = tid & 63;
    unsigned long long lmlt = (1ull << lane) - 1ull;
    int M = cnt[n]; if (M > CAP) M = CAP;
    const uint2* cp = cand + (size_t)n * CAP;

    hf.hist[tid] = 0;
    if (tid == 0) s_pos = 0;
    __syncthreads();

    // ---- phase 1: histogram on top 16 bits of score ----
    for (int i = tid; i < M; i += 1024) {
        unsigned int bits = cp[i].x;
        int bk = (int)(bits >> 16) - 0x3D00;
        bk = max(0, min(1023, bk));
        atomicAdd(&hf.hist[bk], 1);
    }
    __syncthreads();

    // threshold T = max t with suffix-count >= TOPK (wave-0 parallel)
    if (tid < 64) {
        int sl = 0;
        #pragma unroll
        for (int t = 0; t < 16; ++t) sl += hf.hist[tid * 16 + t];
        int incl = sl;
        #pragma unroll
        for (int off = 1; off < 64; off <<= 1) {
            int v = __shfl_down(incl, off);
            if (tid + off < 64) incl += v;
        }
        int xl = incl - sl;
        int tc = -1, cum = xl;
        for (int t = 15; t >= 0; --t) {
            cum += hf.hist[tid * 16 + t];
            if (cum >= TOPK) { tc = tid * 16 + t; break; }
        }
        #pragma unroll
        for (int off = 32; off > 0; off >>= 1)
            tc = max(tc, __shfl_xor(tc, off));
        if (tid == 0) s_T = max(tc, 0);
    }
    __syncthreads();
    int T = s_T;

    // ---- phase 2: collect candidates >= threshold bucket (aggregated atomics) ----
    int iters = (M + 1023) / 1024;
    for (int it = 0; it < iters; ++it) {
        int i = it * 1024 + tid;
        bool pred = false; unsigned long long key = 0ull;
        if (i < M) {
            uint2 e = cp[i];
            int bk = (int)(e.x >> 16) - 0x3D00;
            bk = max(0, min(1023, bk));
            if (bk >= T) {
                pred = true;
                key = ((unsigned long long)e.x << 32) | (unsigned int)(~e.y);
            }
        }
        unsigned long long mask = __ballot(pred);
        int base = 0;
        if (lane == 0) {
            int cw = (int)__popcll(mask);
            if (cw) base = atomicAdd(&s_pos, cw);
        }
        base = __shfl(base, 0);
        if (pred) {
            int pos = base + (int)__popcll(mask & lmlt);
            if (pos < COLCAP) keys[pos] = key;
        }
    }
    __syncthreads();
    int ncol = min(s_pos, COLCAP);

    // ---- phase 3: sort smallest pow2 >= ncol ----
    int nsort = 512;
    while (nsort < ncol) nsort <<= 1;
    for (int i = ncol + tid; i < nsort; i += 1024) keys[i] = 0ull;
    __syncthreads();
    bitonic_desc(keys, nsort, tid, 1024);

    // ---- phase 4: top-400 records into LDS ----
    int nsel = min(TOPK, ncol);
    if (tid < TOPK) {
        int i = tid;
        if (i < nsel) {
            unsigned long long key = keys[i];
            unsigned int bits = (unsigned int)(key >> 32);
            unsigned int flat = ~(unsigned int)key;
            int bb = (int)(flat / NC1);
            int lab = (int)(flat - (unsigned)bb * NC1) + 1;
            float sc = __uint_as_float(bits);
            float4 cb = boxes[(size_t)n * NBOX + bb];
            s_score[i] = sc; s_cbox[i] = cb; s_label[i] = lab;
            float off = 2.0f * (float)lab;
            float4 ob = make_float4(cb.x + off, cb.y + off, cb.z + off, cb.w + off);
            s_ob[i] = ob;
            s_area[i] = fmaxf(ob.z - ob.x, 0.f) * fmaxf(ob.w - ob.y, 0.f);
        } else {
            s_score[i] = -1.0f;
            s_cbox[i] = make_float4(0.f, 0.f, 0.f, 0.f);
            s_label[i] = 0;
            s_ob[i] = make_float4(0.f, 0.f, 0.f, 0.f);
            s_area[i] = 0.f;
        }
    }
    __syncthreads();

    // ---- phase 5: IoU suppression rows (w-major mapping: lanes share w, broadcast j) ----
    for (int t = tid; t < TOPK * KW; t += 1024) {
        int w = t / TOPK;
        int i = t - w * TOPK;
        unsigned long long cur = 0ull;
        if (i < nsel) {
            float4 oi = s_ob[i]; float ai = s_area[i];
            int j0 = w * 64;
            int jend = min(j0 + 64, nsel);
            for (int j = j0; j < jend; ++j) {
                if (j > i) {
                    float4 oj = s_ob[j];
                    float lx = fmaxf(oi.x, oj.x), ly = fmaxf(oi.y, oj.y);
                    float rx = fminf(oi.z, oj.z), ry = fminf(oi.w, oj.w);
                    float inter = fmaxf(rx - lx, 0.f) * fmaxf(ry - ly, 0.f);
                    float uni = fmaxf(ai + s_area[j] - inter, 1e-12f);
                    cur |= ((unsigned long long)(inter / uni > 0.5f)) << (j - j0);
                }
            }
        }
        rows[i * KW + w] = cur;
    }
    __syncthreads();

    // ---- phase 6: serial order-dependent suppression (lane w owns keep word w) ----
    if (tid < 64) {
        unsigned long long keepw = 0ull;
        if (lane < KW) {
            int lo = lane << 6;
            keepw = (nsel >= lo + 64) ? ~0ull
                  : (nsel <= lo ? 0ull : ((1ull << (nsel - lo)) - 1ull));
        }
        unsigned long long row = (lane < KW && nsel > 0) ? rows[lane] : 0ull;
        for (int i = 0; i < nsel; ++i) {
            unsigned long long nrow = (lane < KW && (i + 1) < nsel)
                                      ? rows[(i + 1) * KW + lane] : 0ull;
            unsigned long long kwv = __shfl(keepw, i >> 6);
            if ((kwv >> (i & 63)) & 1ull) keepw &= ~row;
            row = nrow;
        }
        if (lane < KW) s_keep[lane] = keepw;
    }
    __syncthreads();

    // ---- phase 7: final stable top-100 over 400 slots ----
    if (tid < 512) {
        int i = tid;
        unsigned long long key = 0ull;
        if (i < TOPK) {
            bool kb = (s_keep[i >> 6] >> (i & 63)) & 1ull;
            float fv = kb ? s_score[i] : -1.0f;
            key = ((unsigned long long)f2sort(fv) << 32) | (unsigned int)(~i);
        }
        hf.fin[i] = key;
    }
    __syncthreads();
    bitonic_desc(hf.fin, 512, tid, 1024);

    float* obox = out;
    float* olab = out + (size_t)NIMG * MAXOUT * 4;
    float* osco = out + (size_t)NIMG * MAXOUT * 5;
    if (tid < MAXOUT) {
        int k = tid;
        unsigned long long key = hf.fin[k];
        int slot = (int)(~(unsigned int)key);
        float4 cb = make_float4(0.f, 0.f, 0.f, 0.f);
        float lab = 0.f, sv = 0.f;
        if (slot >= 0 && slot < TOPK) {
            bool kb = (s_keep[slot >> 6] >> (slot & 63)) & 1ull;
            float fv = kb ? s_score[slot] : -1.0f;
            if (fv > 0.0f) {
                cb = s_cbox[slot];
                lab = (float)s_label[slot];
                sv = fv;
            }
        }
        size_t bo_ = ((size_t)n * MAXOUT + k) * 4;
        obox[bo_ + 0] = cb.x; obox[bo_ + 1] = cb.y; obox[bo_ + 2] = cb.z; obox[bo_ + 3] = cb.w;
        olab[(size_t)n * MAXOUT + k] = lab;
        osco[(size_t)n * MAXOUT + k] = sv;
    }
}

extern "C" void kernel_launch(void* const* d_in, const int* in_sizes, int n_in,
                              void* d_out, int out_size, void* d_ws, size_t ws_size,
                              hipStream_t stream) {
    (void)in_sizes; (void)n_in; (void)out_size; (void)ws_size;
    const float* bboxes = (const float*)d_in[0];
    const float* scores = (const float*)d_in[1];
    const float* dbox   = (const float*)d_in[2];
    float* out = (float*)d_out;

    char* ws = (char*)d_ws;
    size_t off = 0;
    float4* oboxes = (float4*)(ws + off); off += (size_t)NIMG * NBOX * sizeof(float4);
    int* cnt = (int*)(ws + off); off += 256;
    uint2* cand = (uint2*)(ws + off); off += (size_t)NIMG * CAP * sizeof(uint2);

    hipMemsetAsync(cnt, 0, NIMG * sizeof(int), stream);

    int gx = (NBOX + BDEC - 1) / BDEC;   // 35
    k_decode<<<dim3(gx, NIMG), BDEC, 0, stream>>>(bboxes, scores, dbox, oboxes, cand, cnt);
    k_select<<<NIMG, 1024, 0, stream>>>(oboxes, cand, cnt, out);
}